// Round 8
// baseline (450.890 us; speedup 1.0000x reference)
//
#include <hip/hip_runtime.h>
#include <math.h>

#define SLOPE 0.2f
#define NEG_BIG  -1e30f
#define NEG_BIG2 -2e30f

// ---------------------------------------------------------------- gemm ----
// z[node][o] = sum_k h[node][k] * W[o][k];  h:[n][128], W:[64][128], z:[n][64]
// Block = 64 nodes, 256 threads. W transposed into LDS ws[k][o] (pad 68).
__global__ __launch_bounds__(256) void gemm_kernel(const float* __restrict__ h,
                                                   const float* __restrict__ W,
                                                   float* __restrict__ z, int n) {
    __shared__ float ws[128][68];
    int t = threadIdx.x;
    const float4* __restrict__ W4 = reinterpret_cast<const float4*>(W);
#pragma unroll
    for (int j = 0; j < 8; j++) {
        int idx = t + j * 256;
        float4 w = W4[idx];
        int o = idx >> 5;
        int k = (idx & 31) << 2;
        ws[k + 0][o] = w.x; ws[k + 1][o] = w.y;
        ws[k + 2][o] = w.z; ws[k + 3][o] = w.w;
    }
    __syncthreads();

    int nb = blockIdx.x * 64;
    int ng = t >> 4, og = t & 15;
    int n0 = nb + ng * 4;
    if (n0 >= n) return;
    const float* __restrict__ hp = h + (size_t)n0 * 128;

    float acc[4][4] = {};
#pragma unroll 4
    for (int k = 0; k < 128; k += 4) {
        float4 hv[4], wv[4];
#pragma unroll
        for (int i = 0; i < 4; i++) hv[i] = *(const float4*)(hp + i * 128 + k);
#pragma unroll
        for (int kk = 0; kk < 4; kk++) wv[kk] = *(const float4*)&ws[k + kk][og * 4];
#pragma unroll
        for (int i = 0; i < 4; i++) {
            acc[i][0] += hv[i].x * wv[0].x + hv[i].y * wv[1].x + hv[i].z * wv[2].x + hv[i].w * wv[3].x;
            acc[i][1] += hv[i].x * wv[0].y + hv[i].y * wv[1].y + hv[i].z * wv[2].y + hv[i].w * wv[3].y;
            acc[i][2] += hv[i].x * wv[0].z + hv[i].y * wv[1].z + hv[i].z * wv[2].z + hv[i].w * wv[3].z;
            acc[i][3] += hv[i].x * wv[0].w + hv[i].y * wv[1].w + hv[i].z * wv[2].w + hv[i].w * wv[3].w;
        }
    }
#pragma unroll
    for (int i = 0; i < 4; i++) {
        *(float4*)&z[(size_t)(n0 + i) * 64 + og * 4] =
            make_float4(acc[i][0], acc[i][1], acc[i][2], acc[i][3]);
    }
}

// ------------------------------------------------- histogram (int4) ------
__global__ __launch_bounds__(256) void hist4_kernel(const int* __restrict__ dst,
                                                    int* __restrict__ cnt, int ne) {
    int i = blockIdx.x * 256 + threadIdx.x;
    int base = i * 4;
    if (base + 3 < ne) {
        int4 d = *(const int4*)(dst + base);
        atomicAdd(&cnt[d.x], 1); atomicAdd(&cnt[d.y], 1);
        atomicAdd(&cnt[d.z], 1); atomicAdd(&cnt[d.w], 1);
    } else {
        for (int r = base; r < ne; r++) atomicAdd(&cnt[dst[r]], 1);
    }
}

// ----------------------- single-block full scan (cnt -> starts,cursor) ---
// cnt may alias cursor (read-before-write within each tile).
__global__ __launch_bounds__(1024) void scan_all(const int* __restrict__ cnt,
                                                 int* __restrict__ starts,
                                                 int* __restrict__ cursor,
                                                 int n, int ne) {
    __shared__ int ls[1024];
    int tid = threadIdx.x;
    int carry = 0;
    for (int base = 0; base < n; base += 16384) {
        int v[16]; int s = 0;
        int idx0 = base + tid * 16;
#pragma unroll
        for (int k = 0; k < 16; k++) {
            int idx = idx0 + k;
            int c = idx < n ? cnt[idx] : 0;
            v[k] = c; s += c;
        }
        ls[tid] = s;
        __syncthreads();
        for (int off = 1; off < 1024; off <<= 1) {
            int t = tid >= off ? ls[tid - off] : 0;
            __syncthreads();
            ls[tid] += t;
            __syncthreads();
        }
        int run = carry + ls[tid] - s;
        int tot = ls[1023];
#pragma unroll
        for (int k = 0; k < 16; k++) {
            int idx = idx0 + k;
            if (idx < n) { starts[idx] = run; cursor[idx] = run; }
            run += v[k];
        }
        carry += tot;
        __syncthreads();
    }
    if (tid == 0) starts[n] = ne;
}

// ------------------------------- scatter src indices into CSR (int4) -----
__global__ __launch_bounds__(256) void scatter4_kernel(const int* __restrict__ src,
                                                       const int* __restrict__ dst,
                                                       int* __restrict__ cursor,
                                                       int* __restrict__ csr_src, int ne) {
    int i = blockIdx.x * 256 + threadIdx.x;
    int base = i * 4;
    if (base + 3 < ne) {
        int4 s = *(const int4*)(src + base);
        int4 d = *(const int4*)(dst + base);
        int p0 = atomicAdd(&cursor[d.x], 1); csr_src[p0] = s.x;
        int p1 = atomicAdd(&cursor[d.y], 1); csr_src[p1] = s.y;
        int p2 = atomicAdd(&cursor[d.z], 1); csr_src[p2] = s.z;
        int p3 = atomicAdd(&cursor[d.w], 1); csr_src[p3] = s.w;
    } else {
        for (int r = base; r < ne; r++) {
            int p = atomicAdd(&cursor[dst[r]], 1);
            csr_src[p] = src[r];
        }
    }
}

// ------------- fused: dot + online softmax + aggregation + elu -----------
// One wave per node. lane = (g,q): g = edge slot (0..3), q = channel quad
// (0..15). One dwordx4 gather per lane fetches 4 edge rows per iteration
// (1KB/wave-instr). Dot = 4 FMA + 4-step butterfly within 16-lane group.
// Branch-free online softmax with finite sentinels; group states merged by
// 2 butterfly rounds at the end.
__global__ __launch_bounds__(256) void fused_node(const float4* __restrict__ z4,
                                                  const int* __restrict__ starts,
                                                  const int* __restrict__ csr_src,
                                                  float4* __restrict__ out4, int n) {
    int node = blockIdx.x * 4 + (threadIdx.x >> 6);
    if (node >= n) return;
    int lane = threadIdx.x & 63;
    int g = lane >> 4;
    int q = lane & 15;
    int rs = starts[node], re = starts[node + 1];
    float4 zd = z4[(size_t)node * 16 + q];

    float m = NEG_BIG, denom = 0.f;
    float4 acc = make_float4(0.f, 0.f, 0.f, 0.f);

    for (int c = rs; c < re; c += 64) {
        int j = c + lane;
        int sv = j < re ? csr_src[j] : 0;
        int cn = min(64, re - c);
        // prologue gather (k=0); index clamped so the row is always valid
        int idx = g;
        bool val = idx < cn;
        int s = __shfl(sv, val ? idx : 0);
        float4 v = z4[(size_t)s * 16 + q];
        for (int k = 0; k < cn; k += 4) {
            // prefetch next 4 rows (clamped index, always-load: no garbage)
            int idx_n = k + 4 + g;
            bool val_n = idx_n < cn;
            int s_n = __shfl(sv, val_n ? idx_n : 0);
            float4 vn = z4[(size_t)s_n * 16 + q];
            // dot over own 4 channels, butterfly over 16-lane group
            float p = v.x * zd.x + v.y * zd.y + v.z * zd.z + v.w * zd.w;
#pragma unroll
            for (int msk = 1; msk < 16; msk <<= 1) p += __shfl_xor(p, msk);
            float e = p > 0.f ? p : SLOPE * p;
            e = val ? e : NEG_BIG2;
            float mnew = fmaxf(m, e);
            float sc = __expf(m - mnew);   // ==1 when no new max; ==0 on first edge
            float ex = __expf(e - mnew);   // ==0 for invalid slots
            denom = denom * sc + ex;
            acc.x = acc.x * sc + ex * v.x;
            acc.y = acc.y * sc + ex * v.y;
            acc.z = acc.z * sc + ex * v.z;
            acc.w = acc.w * sc + ex * v.w;
            m = mnew;
            v = vn; val = val_n;
        }
    }
    // merge the 4 group states (same q across groups): masks 16, 32
#pragma unroll
    for (int msk = 16; msk < 64; msk <<= 1) {
        float mo  = __shfl_xor(m, msk);
        float dno = __shfl_xor(denom, msk);
        float ax = __shfl_xor(acc.x, msk);
        float ay = __shfl_xor(acc.y, msk);
        float az = __shfl_xor(acc.z, msk);
        float aw = __shfl_xor(acc.w, msk);
        float mnew = fmaxf(m, mo);
        float ss = __expf(m - mnew), so = __expf(mo - mnew);
        denom = denom * ss + dno * so;
        acc.x = acc.x * ss + ax * so;
        acc.y = acc.y * ss + ay * so;
        acc.z = acc.z * ss + az * so;
        acc.w = acc.w * ss + aw * so;
        m = mnew;
    }
    if (lane < 16) {
        float inv = denom > 0.f ? 1.f / denom : 0.f;
        float4 r; float x;
        x = acc.x * inv; r.x = x > 0.f ? x : expm1f(x);
        x = acc.y * inv; r.y = x > 0.f ? x : expm1f(x);
        x = acc.z * inv; r.z = x > 0.f ? x : expm1f(x);
        x = acc.w * inv; r.w = x > 0.f ? x : expm1f(x);
        out4[(size_t)node * 16 + q] = r;
    }
}

// -------------------------------------------------------------- launch ----
extern "C" void kernel_launch(void* const* d_in, const int* in_sizes, int n_in,
                              void* d_out, int out_size, void* d_ws, size_t ws_size,
                              hipStream_t stream) {
    const float* h   = (const float*)d_in[0];
    const float* W   = (const float*)d_in[1];
    const int*   src = (const int*)d_in[2];
    const int*   dst = (const int*)d_in[3];
    int n  = in_sizes[0] / 128;   // 100000
    int ne = in_sizes[2];         // 1600000

    float* z       = (float*)d_ws;                    // n*64 floats
    int*   starts  = (int*)(z + (size_t)n * 64);      // n+1 ints
    int*   cursor  = starts + (n + 1);                // n ints (histogram too)
    int*   csr_src = cursor + n;                      // ne ints

    int nt4 = (ne + 3) / 4;

    hipMemsetAsync(cursor, 0, (size_t)n * sizeof(int), stream);
    gemm_kernel<<<(n + 63) / 64, 256, 0, stream>>>(h, W, z, n);
    hist4_kernel<<<(nt4 + 255) / 256, 256, 0, stream>>>(dst, cursor, ne);
    scan_all<<<1, 1024, 0, stream>>>(cursor, starts, cursor, n, ne);
    scatter4_kernel<<<(nt4 + 255) / 256, 256, 0, stream>>>(src, dst, cursor, csr_src, ne);
    fused_node<<<(n + 3) / 4, 256, 0, stream>>>((const float4*)z, starts, csr_src,
                                                (float4*)d_out, n);
}

// Round 9
// 229.428 us; speedup vs baseline: 1.9653x; 1.9653x over previous
//
#include <hip/hip_runtime.h>
#include <math.h>

#define SLOPE 0.2f
#define NEG_BIG  -1e30f
#define NEG_BIG2 -2e30f

// ---------------------------------------------------------------- gemm ----
// z[node][o] = sum_k h[node][k] * W[o][k];  h:[n][128], W:[64][128], z:[n][64]
// Block = 64 nodes, 256 threads. W transposed into LDS ws[k][o] (pad 68).
__global__ __launch_bounds__(256) void gemm_kernel(const float* __restrict__ h,
                                                   const float* __restrict__ W,
                                                   float* __restrict__ z, int n) {
    __shared__ float ws[128][68];
    int t = threadIdx.x;
    const float4* __restrict__ W4 = reinterpret_cast<const float4*>(W);
#pragma unroll
    for (int j = 0; j < 8; j++) {
        int idx = t + j * 256;
        float4 w = W4[idx];
        int o = idx >> 5;
        int k = (idx & 31) << 2;
        ws[k + 0][o] = w.x; ws[k + 1][o] = w.y;
        ws[k + 2][o] = w.z; ws[k + 3][o] = w.w;
    }
    __syncthreads();

    int nb = blockIdx.x * 64;
    int ng = t >> 4, og = t & 15;
    int n0 = nb + ng * 4;
    if (n0 >= n) return;
    const float* __restrict__ hp = h + (size_t)n0 * 128;

    float acc[4][4] = {};
#pragma unroll 4
    for (int k = 0; k < 128; k += 4) {
        float4 hv[4], wv[4];
#pragma unroll
        for (int i = 0; i < 4; i++) hv[i] = *(const float4*)(hp + i * 128 + k);
#pragma unroll
        for (int kk = 0; kk < 4; kk++) wv[kk] = *(const float4*)&ws[k + kk][og * 4];
#pragma unroll
        for (int i = 0; i < 4; i++) {
            acc[i][0] += hv[i].x * wv[0].x + hv[i].y * wv[1].x + hv[i].z * wv[2].x + hv[i].w * wv[3].x;
            acc[i][1] += hv[i].x * wv[0].y + hv[i].y * wv[1].y + hv[i].z * wv[2].y + hv[i].w * wv[3].y;
            acc[i][2] += hv[i].x * wv[0].z + hv[i].y * wv[1].z + hv[i].z * wv[2].z + hv[i].w * wv[3].z;
            acc[i][3] += hv[i].x * wv[0].w + hv[i].y * wv[1].w + hv[i].z * wv[2].w + hv[i].w * wv[3].w;
        }
    }
#pragma unroll
    for (int i = 0; i < 4; i++) {
        *(float4*)&z[(size_t)(n0 + i) * 64 + og * 4] =
            make_float4(acc[i][0], acc[i][1], acc[i][2], acc[i][3]);
    }
}

// ----------------------------- histogram (int4) + per-edge rank ----------
__global__ __launch_bounds__(256) void hist4_kernel(const int* __restrict__ dst,
                                                    int* __restrict__ cnt,
                                                    int* __restrict__ rank, int ne) {
    int i = blockIdx.x * 256 + threadIdx.x;
    int base = i * 4;
    if (base + 3 < ne) {
        int4 d = *(const int4*)(dst + base);
        int4 r;
        r.x = atomicAdd(&cnt[d.x], 1);
        r.y = atomicAdd(&cnt[d.y], 1);
        r.z = atomicAdd(&cnt[d.z], 1);
        r.w = atomicAdd(&cnt[d.w], 1);
        *(int4*)(rank + base) = r;
    } else {
        for (int r = base; r < ne; r++) rank[r] = atomicAdd(&cnt[dst[r]], 1);
    }
}

// ------------------------------------------------- scan (4096/block) -----
__global__ __launch_bounds__(256) void scan1(const int* __restrict__ cnt,
                                             int* __restrict__ starts,
                                             int* __restrict__ bsums, int n) {
    __shared__ int ls[256];
    int tbase = blockIdx.x * 4096 + threadIdx.x * 16;
    int v[16];
    int s = 0;
#pragma unroll
    for (int k = 0; k < 16; k++) {
        int idx = tbase + k;
        int c = idx < n ? cnt[idx] : 0;
        v[k] = c; s += c;
    }
    ls[threadIdx.x] = s;
    __syncthreads();
    for (int off = 1; off < 256; off <<= 1) {
        int t = threadIdx.x >= off ? ls[threadIdx.x - off] : 0;
        __syncthreads();
        ls[threadIdx.x] += t;
        __syncthreads();
    }
    int run = ls[threadIdx.x] - s;   // exclusive prefix within block
    if (threadIdx.x == 255) bsums[blockIdx.x] = ls[255];
#pragma unroll
    for (int k = 0; k < 16; k++) {
        int idx = tbase + k;
        if (idx < n) starts[idx] = run;
        run += v[k];
    }
}

__global__ void scan2(int* __restrict__ bsums, int nb, int* __restrict__ starts,
                      int n, int ne) {
    if (threadIdx.x == 0) {
        int run = 0;
        for (int b = 0; b < nb; b++) { int t = bsums[b]; bsums[b] = run; run += t; }
        starts[n] = ne;
    }
}

__global__ __launch_bounds__(256) void scan3(int* __restrict__ starts,
                                             const int* __restrict__ bsums, int n) {
    int i = blockIdx.x * 256 + threadIdx.x;
    if (i < n) starts[i] += bsums[i >> 12];
}

// --------------------- scatter src indices into CSR (rank-based) ---------
__global__ __launch_bounds__(256) void scatter4_kernel(const int* __restrict__ src,
                                                       const int* __restrict__ dst,
                                                       const int* __restrict__ starts,
                                                       const int* __restrict__ rank,
                                                       int* __restrict__ csr_src, int ne) {
    int i = blockIdx.x * 256 + threadIdx.x;
    int base = i * 4;
    if (base + 3 < ne) {
        int4 s = *(const int4*)(src + base);
        int4 d = *(const int4*)(dst + base);
        int4 r = *(const int4*)(rank + base);
        csr_src[starts[d.x] + r.x] = s.x;
        csr_src[starts[d.y] + r.y] = s.y;
        csr_src[starts[d.z] + r.z] = s.z;
        csr_src[starts[d.w] + r.w] = s.w;
    } else {
        for (int r = base; r < ne; r++)
            csr_src[starts[dst[r]] + rank[r]] = src[r];
    }
}

// ------------- fused: dot + online softmax + aggregation + elu -----------
// One wave per node. lane = (g,q): g = edge slot (0..3), q = channel quad
// (0..15). One dwordx4 gather per lane fetches 4 edge rows per iteration.
__global__ __launch_bounds__(256) void fused_node(const float4* __restrict__ z4,
                                                  const int* __restrict__ starts,
                                                  const int* __restrict__ csr_src,
                                                  float4* __restrict__ out4, int n) {
    int node = blockIdx.x * 4 + (threadIdx.x >> 6);
    if (node >= n) return;
    int lane = threadIdx.x & 63;
    int g = lane >> 4;
    int q = lane & 15;
    int rs = starts[node], re = starts[node + 1];
    float4 zd = z4[(size_t)node * 16 + q];

    float m = NEG_BIG, denom = 0.f;
    float4 acc = make_float4(0.f, 0.f, 0.f, 0.f);

    for (int c = rs; c < re; c += 64) {
        int j = c + lane;
        int sv = j < re ? csr_src[j] : 0;
        int cn = min(64, re - c);
        int idx = g;
        bool val = idx < cn;
        int s = __shfl(sv, val ? idx : 0);
        float4 v = z4[(size_t)s * 16 + q];
        for (int k = 0; k < cn; k += 4) {
            int idx_n = k + 4 + g;
            bool val_n = idx_n < cn;
            int s_n = __shfl(sv, val_n ? idx_n : 0);
            float4 vn = z4[(size_t)s_n * 16 + q];
            float p = v.x * zd.x + v.y * zd.y + v.z * zd.z + v.w * zd.w;
#pragma unroll
            for (int msk = 1; msk < 16; msk <<= 1) p += __shfl_xor(p, msk);
            float e = p > 0.f ? p : SLOPE * p;
            e = val ? e : NEG_BIG2;
            float mnew = fmaxf(m, e);
            float sc = __expf(m - mnew);
            float ex = __expf(e - mnew);
            denom = denom * sc + ex;
            acc.x = acc.x * sc + ex * v.x;
            acc.y = acc.y * sc + ex * v.y;
            acc.z = acc.z * sc + ex * v.z;
            acc.w = acc.w * sc + ex * v.w;
            m = mnew;
            v = vn; val = val_n;
        }
    }
#pragma unroll
    for (int msk = 16; msk < 64; msk <<= 1) {
        float mo  = __shfl_xor(m, msk);
        float dno = __shfl_xor(denom, msk);
        float ax = __shfl_xor(acc.x, msk);
        float ay = __shfl_xor(acc.y, msk);
        float az = __shfl_xor(acc.z, msk);
        float aw = __shfl_xor(acc.w, msk);
        float mnew = fmaxf(m, mo);
        float ss = __expf(m - mnew), so = __expf(mo - mnew);
        denom = denom * ss + dno * so;
        acc.x = acc.x * ss + ax * so;
        acc.y = acc.y * ss + ay * so;
        acc.z = acc.z * ss + az * so;
        acc.w = acc.w * ss + aw * so;
        m = mnew;
    }
    if (lane < 16) {
        float inv = denom > 0.f ? 1.f / denom : 0.f;
        float4 r; float x;
        x = acc.x * inv; r.x = x > 0.f ? x : expm1f(x);
        x = acc.y * inv; r.y = x > 0.f ? x : expm1f(x);
        x = acc.z * inv; r.z = x > 0.f ? x : expm1f(x);
        x = acc.w * inv; r.w = x > 0.f ? x : expm1f(x);
        out4[(size_t)node * 16 + q] = r;
    }
}

// -------------------------------------------------------------- launch ----
extern "C" void kernel_launch(void* const* d_in, const int* in_sizes, int n_in,
                              void* d_out, int out_size, void* d_ws, size_t ws_size,
                              hipStream_t stream) {
    const float* h   = (const float*)d_in[0];
    const float* W   = (const float*)d_in[1];
    const int*   src = (const int*)d_in[2];
    const int*   dst = (const int*)d_in[3];
    int n  = in_sizes[0] / 128;   // 100000
    int ne = in_sizes[2];         // 1600000

    float* z       = (float*)d_ws;                    // n*64 floats
    int*   starts  = (int*)(z + (size_t)n * 64);      // n+1 ints
    int*   cnt     = starts + (n + 1);                // n ints
    int*   rank    = cnt + n;                         // ne ints
    int*   csr_src = rank + ne;                       // ne ints
    int*   bsums   = csr_src + ne;                    // 32 ints

    int nt4 = (ne + 3) / 4;
    int nb_scan = (n + 4095) / 4096;                  // 25

    hipMemsetAsync(cnt, 0, (size_t)n * sizeof(int), stream);
    gemm_kernel<<<(n + 63) / 64, 256, 0, stream>>>(h, W, z, n);
    hist4_kernel<<<(nt4 + 255) / 256, 256, 0, stream>>>(dst, cnt, rank, ne);
    scan1<<<nb_scan, 256, 0, stream>>>(cnt, starts, bsums, n);
    scan2<<<1, 64, 0, stream>>>(bsums, nb_scan, starts, n, ne);
    scan3<<<(n + 255) / 256, 256, 0, stream>>>(starts, bsums, n);
    scatter4_kernel<<<(nt4 + 255) / 256, 256, 0, stream>>>(src, dst, starts, rank,
                                                           csr_src, ne);
    fused_node<<<(n + 3) / 4, 256, 0, stream>>>((const float4*)z, starts, csr_src,
                                                (float4*)d_out, n);
}

// Round 13
// 211.747 us; speedup vs baseline: 2.1294x; 1.0835x over previous
//
#include <hip/hip_runtime.h>
#include <math.h>

#define SLOPE 0.2f
#define LOG2E 1.4426950408889634f

// --------------------------- fused gemm + histogram ----------------------
// gemm: z[node][o] = sum_k h[node][k]*W[o][k]; block = 64 nodes, 256 thr,
// W transposed into LDS (pad 68). hist: same grid covers 4 edges/thread;
// its atomic latency hides under the FMA work.
__global__ __launch_bounds__(256) void gemm_hist_kernel(const float* __restrict__ h,
                                                        const float* __restrict__ W,
                                                        float* __restrict__ z,
                                                        const int* __restrict__ dst,
                                                        int* __restrict__ cnt,
                                                        int* __restrict__ rank,
                                                        int n, int ne) {
    // ---- histogram part (before any early return) ----
    int ei = blockIdx.x * 256 + threadIdx.x;
    int base = ei * 4;
    if (base + 3 < ne) {
        int4 d = *(const int4*)(dst + base);
        int4 r;
        r.x = atomicAdd(&cnt[d.x], 1);
        r.y = atomicAdd(&cnt[d.y], 1);
        r.z = atomicAdd(&cnt[d.z], 1);
        r.w = atomicAdd(&cnt[d.w], 1);
        *(int4*)(rank + base) = r;
    } else if (base < ne) {
        for (int rr = base; rr < ne; rr++) rank[rr] = atomicAdd(&cnt[dst[rr]], 1);
    }

    // ---- gemm part ----
    __shared__ float ws[128][68];
    int t = threadIdx.x;
    const float4* __restrict__ W4 = reinterpret_cast<const float4*>(W);
#pragma unroll
    for (int j = 0; j < 8; j++) {
        int idx = t + j * 256;
        float4 w = W4[idx];
        int o = idx >> 5;
        int k = (idx & 31) << 2;
        ws[k + 0][o] = w.x; ws[k + 1][o] = w.y;
        ws[k + 2][o] = w.z; ws[k + 3][o] = w.w;
    }
    __syncthreads();

    int nb = blockIdx.x * 64;
    int ng = t >> 4, og = t & 15;
    int n0 = nb + ng * 4;
    if (n0 >= n) return;
    const float* __restrict__ hp = h + (size_t)n0 * 128;

    float acc[4][4] = {};
#pragma unroll 4
    for (int k = 0; k < 128; k += 4) {
        float4 hv[4], wv[4];
#pragma unroll
        for (int i = 0; i < 4; i++) hv[i] = *(const float4*)(hp + i * 128 + k);
#pragma unroll
        for (int kk = 0; kk < 4; kk++) wv[kk] = *(const float4*)&ws[k + kk][og * 4];
#pragma unroll
        for (int i = 0; i < 4; i++) {
            acc[i][0] += hv[i].x * wv[0].x + hv[i].y * wv[1].x + hv[i].z * wv[2].x + hv[i].w * wv[3].x;
            acc[i][1] += hv[i].x * wv[0].y + hv[i].y * wv[1].y + hv[i].z * wv[2].y + hv[i].w * wv[3].y;
            acc[i][2] += hv[i].x * wv[0].z + hv[i].y * wv[1].z + hv[i].z * wv[2].z + hv[i].w * wv[3].z;
            acc[i][3] += hv[i].x * wv[0].w + hv[i].y * wv[1].w + hv[i].z * wv[2].w + hv[i].w * wv[3].w;
        }
    }
#pragma unroll
    for (int i = 0; i < 4; i++) {
        *(float4*)&z[(size_t)(n0 + i) * 64 + og * 4] =
            make_float4(acc[i][0], acc[i][1], acc[i][2], acc[i][3]);
    }
}

// ------------------------------------------------- scan (4096/block) -----
__global__ __launch_bounds__(256) void scan1(const int* __restrict__ cnt,
                                             int* __restrict__ starts,
                                             int* __restrict__ bsums, int n) {
    __shared__ int ls[256];
    int tbase = blockIdx.x * 4096 + threadIdx.x * 16;
    int v[16];
    int s = 0;
#pragma unroll
    for (int k = 0; k < 16; k++) {
        int idx = tbase + k;
        int c = idx < n ? cnt[idx] : 0;
        v[k] = c; s += c;
    }
    ls[threadIdx.x] = s;
    __syncthreads();
    for (int off = 1; off < 256; off <<= 1) {
        int t = threadIdx.x >= off ? ls[threadIdx.x - off] : 0;
        __syncthreads();
        ls[threadIdx.x] += t;
        __syncthreads();
    }
    int run = ls[threadIdx.x] - s;
    if (threadIdx.x == 255) bsums[blockIdx.x] = ls[255];
#pragma unroll
    for (int k = 0; k < 16; k++) {
        int idx = tbase + k;
        if (idx < n) starts[idx] = run;
        run += v[k];
    }
}

__global__ void scan2(int* __restrict__ bsums, int nb, int* __restrict__ starts,
                      int n, int ne) {
    if (threadIdx.x == 0) {
        int run = 0;
        for (int b = 0; b < nb; b++) { int t = bsums[b]; bsums[b] = run; run += t; }
        starts[n] = ne;
    }
}

__global__ __launch_bounds__(256) void scan3(int* __restrict__ starts,
                                             const int* __restrict__ bsums, int n) {
    int i = blockIdx.x * 256 + threadIdx.x;
    if (i < n) starts[i] += bsums[i >> 12];
}

// --------------------- scatter src indices into CSR (rank-based) ---------
__global__ __launch_bounds__(256) void scatter4_kernel(const int* __restrict__ src,
                                                       const int* __restrict__ dst,
                                                       const int* __restrict__ starts,
                                                       const int* __restrict__ rank,
                                                       int* __restrict__ csr_src, int ne) {
    int i = blockIdx.x * 256 + threadIdx.x;
    int base = i * 4;
    if (base + 3 < ne) {
        int4 s = *(const int4*)(src + base);
        int4 d = *(const int4*)(dst + base);
        int4 r = *(const int4*)(rank + base);
        csr_src[starts[d.x] + r.x] = s.x;
        csr_src[starts[d.y] + r.y] = s.y;
        csr_src[starts[d.z] + r.z] = s.z;
        csr_src[starts[d.w] + r.w] = s.w;
    } else {
        for (int r = base; r < ne; r++)
            csr_src[starts[dst[r]] + rank[r]] = src[r];
    }
}

// ------------- fused: dot + online softmax + aggregation + elu -----------
// One wave per node. lane = (g,q): g = edge slot (0..3), q = channel quad.
// exp2-domain online softmax with wave-uniform fast path (no max growth ->
// no rescale). One dwordx4 gather per lane fetches 4 edge rows per iter.
__global__ __launch_bounds__(256) void fused_node(const float4* __restrict__ z4,
                                                  const int* __restrict__ starts,
                                                  const int* __restrict__ csr_src,
                                                  float4* __restrict__ out4, int n) {
    int node = blockIdx.x * 4 + (threadIdx.x >> 6);
    if (node >= n) return;
    int lane = threadIdx.x & 63;
    int g = lane >> 4;
    int q = lane & 15;
    int rs = starts[node], re = starts[node + 1];
    float4 zd = z4[(size_t)node * 16 + q];

    float m2 = -1e30f, denom = 0.f;
    float4 acc = make_float4(0.f, 0.f, 0.f, 0.f);

    for (int c = rs; c < re; c += 64) {
        int j = c + lane;
        int sv = j < re ? csr_src[j] : 0;
        int cn = min(64, re - c);
        int idx = g;
        bool val = idx < cn;
        int s = __shfl(sv, val ? idx : 0);
        float4 v = z4[(size_t)s * 16 + q];
        for (int k = 0; k < cn; k += 4) {
            int idx_n = k + 4 + g;
            bool val_n = idx_n < cn;
            int s_n = __shfl(sv, val_n ? idx_n : 0);
            float4 vn = z4[(size_t)s_n * 16 + q];
            float p = v.x * zd.x + v.y * zd.y + v.z * zd.z + v.w * zd.w;
#pragma unroll
            for (int msk = 1; msk < 16; msk <<= 1) p += __shfl_xor(p, msk);
            float e = p > 0.f ? p : SLOPE * p;
            float e2 = e * LOG2E;
            e2 = val ? e2 : -2e30f;
            if (__any(e2 > m2)) {                 // max grew somewhere: rescale
                float mnew = fmaxf(m2, e2);
                float sc = exp2f(m2 - mnew);      // ==0 on first edge
                float ex = exp2f(e2 - mnew);      // ==0 for invalid slots
                denom = fmaf(denom, sc, ex);
                acc.x = fmaf(acc.x, sc, ex * v.x);
                acc.y = fmaf(acc.y, sc, ex * v.y);
                acc.z = fmaf(acc.z, sc, ex * v.z);
                acc.w = fmaf(acc.w, sc, ex * v.w);
                m2 = mnew;
            } else {                              // fast path: no rescale
                float ex = exp2f(e2 - m2);
                denom += ex;
                acc.x = fmaf(ex, v.x, acc.x);
                acc.y = fmaf(ex, v.y, acc.y);
                acc.z = fmaf(ex, v.z, acc.z);
                acc.w = fmaf(ex, v.w, acc.w);
            }
            v = vn; val = val_n;
        }
    }
    // merge the 4 group states (same q across groups)
#pragma unroll
    for (int msk = 16; msk < 64; msk <<= 1) {
        float mo  = __shfl_xor(m2, msk);
        float dno = __shfl_xor(denom, msk);
        float ax = __shfl_xor(acc.x, msk);
        float ay = __shfl_xor(acc.y, msk);
        float az = __shfl_xor(acc.z, msk);
        float aw = __shfl_xor(acc.w, msk);
        float mnew = fmaxf(m2, mo);
        float ss = exp2f(m2 - mnew), so = exp2f(mo - mnew);
        denom = fmaf(denom, ss, dno * so);
        acc.x = fmaf(acc.x, ss, ax * so);
        acc.y = fmaf(acc.y, ss, ay * so);
        acc.z = fmaf(acc.z, ss, az * so);
        acc.w = fmaf(acc.w, ss, aw * so);
        m2 = mnew;
    }
    if (lane < 16) {
        float inv = denom > 0.f ? 1.f / denom : 0.f;
        float4 r; float x;
        x = acc.x * inv; r.x = x > 0.f ? x : __expf(x) - 1.f;
        x = acc.y * inv; r.y = x > 0.f ? x : __expf(x) - 1.f;
        x = acc.z * inv; r.z = x > 0.f ? x : __expf(x) - 1.f;
        x = acc.w * inv; r.w = x > 0.f ? x : __expf(x) - 1.f;
        out4[(size_t)node * 16 + q] = r;
    }
}

// -------------------------------------------------------------- launch ----
extern "C" void kernel_launch(void* const* d_in, const int* in_sizes, int n_in,
                              void* d_out, int out_size, void* d_ws, size_t ws_size,
                              hipStream_t stream) {
    const float* h   = (const float*)d_in[0];
    const float* W   = (const float*)d_in[1];
    const int*   src = (const int*)d_in[2];
    const int*   dst = (const int*)d_in[3];
    int n  = in_sizes[0] / 128;   // 100000
    int ne = in_sizes[2];         // 1600000

    float* z       = (float*)d_ws;                    // n*64 floats
    int*   starts  = (int*)(z + (size_t)n * 64);      // n+1 ints
    int*   cnt     = starts + (n + 1);                // n ints
    int*   rank    = cnt + n;                         // ne ints
    int*   csr_src = rank + ne;                       // ne ints
    int*   bsums   = csr_src + ne;                    // 32 ints

    int nb_gemm = (n + 63) / 64;                      // 1563 (covers ne/1024 too)
    int nt4 = (ne + 3) / 4;
    int nb_scan = (n + 4095) / 4096;                  // 25

    hipMemsetAsync(cnt, 0, (size_t)n * sizeof(int), stream);
    gemm_hist_kernel<<<nb_gemm, 256, 0, stream>>>(h, W, z, dst, cnt, rank, n, ne);
    scan1<<<nb_scan, 256, 0, stream>>>(cnt, starts, bsums, n);
    scan2<<<1, 64, 0, stream>>>(bsums, nb_scan, starts, n, ne);
    scan3<<<(n + 255) / 256, 256, 0, stream>>>(starts, bsums, n);
    scatter4_kernel<<<(nt4 + 255) / 256, 256, 0, stream>>>(src, dst, starts, rank,
                                                           csr_src, ne);
    fused_node<<<(n + 3) / 4, 256, 0, stream>>>((const float4*)z, starts, csr_src,
                                                (float4*)d_out, n);
}

// Round 14
// 205.672 us; speedup vs baseline: 2.1923x; 1.0295x over previous
//
#include <hip/hip_runtime.h>
#include <math.h>

#define SLOPE 0.2f
#define LOG2E 1.4426950408889634f

// --------------------------- fused gemm + histogram ----------------------
// gemm: z[node][o] = sum_k h[node][k]*W[o][k]. Block = 64 nodes x 32 chans
// (blockIdx&1 selects channel half), 256 threads, 2x4 register tile.
// W^T staged in LDS [128][36] with XOR swizzle (store 2-way, read 0-way).
// hist: 2 edges/thread across the whole grid; atomics hide under FMA.
__global__ __launch_bounds__(256, 8) void gemm_hist_kernel(const float* __restrict__ h,
                                                           const float* __restrict__ W,
                                                           float* __restrict__ z,
                                                           const int* __restrict__ dst,
                                                           int* __restrict__ cnt,
                                                           int* __restrict__ rank,
                                                           int n, int ne) {
    // ---- histogram part (before any early return) ----
    int ei = blockIdx.x * 256 + threadIdx.x;
    int base = ei * 2;
    if (base + 1 < ne) {
        int2 d = *(const int2*)(dst + base);
        int2 r;
        r.x = atomicAdd(&cnt[d.x], 1);
        r.y = atomicAdd(&cnt[d.y], 1);
        *(int2*)(rank + base) = r;
    } else if (base < ne) {
        rank[base] = atomicAdd(&cnt[dst[base]], 1);
    }

    // ---- gemm part ----
    __shared__ float ws[128][36];     // 18.4 KB, W^T (swizzled cols)
    int t = threadIdx.x;
    int nblk = blockIdx.x >> 1;
    int ch0  = (blockIdx.x & 1) << 5;
    const float4* __restrict__ W4 = reinterpret_cast<const float4*>(W);
#pragma unroll
    for (int j = 0; j < 4; j++) {
        int idx = t + j * 256;            // 0..1023
        int o  = idx >> 5;                // 0..31 (local channel)
        int kq = idx & 31;                // float4 col index
        float4 w = W4[(size_t)(ch0 + o) * 32 + kq];
        int k = kq << 2;
        int col = o ^ ((kq & 7) << 2);    // XOR swizzle on og bits
        ws[k + 0][col] = w.x; ws[k + 1][col] = w.y;
        ws[k + 2][col] = w.z; ws[k + 3][col] = w.w;
    }
    __syncthreads();

    int ng = t >> 3, og = t & 7;
    int n0 = nblk * 64 + ng * 2;
    if (n0 >= n) return;                  // n even: rows n0, n0+1 both valid
    const float* __restrict__ hp = h + (size_t)n0 * 128;

    float acc[2][4] = {};
#pragma unroll 4
    for (int k = 0; k < 128; k += 4) {
        int m = (k >> 2) & 7;
        int colb = (og ^ m) << 2;
        float4 hv[2], wv[4];
#pragma unroll
        for (int i = 0; i < 2; i++) hv[i] = *(const float4*)(hp + i * 128 + k);
#pragma unroll
        for (int kk = 0; kk < 4; kk++) wv[kk] = *(const float4*)&ws[k + kk][colb];
#pragma unroll
        for (int i = 0; i < 2; i++) {
            acc[i][0] += hv[i].x * wv[0].x + hv[i].y * wv[1].x + hv[i].z * wv[2].x + hv[i].w * wv[3].x;
            acc[i][1] += hv[i].x * wv[0].y + hv[i].y * wv[1].y + hv[i].z * wv[2].y + hv[i].w * wv[3].y;
            acc[i][2] += hv[i].x * wv[0].z + hv[i].y * wv[1].z + hv[i].z * wv[2].z + hv[i].w * wv[3].z;
            acc[i][3] += hv[i].x * wv[0].w + hv[i].y * wv[1].w + hv[i].z * wv[2].w + hv[i].w * wv[3].w;
        }
    }
#pragma unroll
    for (int i = 0; i < 2; i++) {
        *(float4*)&z[(size_t)(n0 + i) * 64 + ch0 + og * 4] =
            make_float4(acc[i][0], acc[i][1], acc[i][2], acc[i][3]);
    }
}

// ------------------------------------------------- scan (4096/block) -----
__global__ __launch_bounds__(256) void scan1(const int* __restrict__ cnt,
                                             int* __restrict__ starts,
                                             int* __restrict__ bsums, int n) {
    __shared__ int ls[256];
    int tbase = blockIdx.x * 4096 + threadIdx.x * 16;
    int v[16];
    int s = 0;
#pragma unroll
    for (int k = 0; k < 16; k++) {
        int idx = tbase + k;
        int c = idx < n ? cnt[idx] : 0;
        v[k] = c; s += c;
    }
    ls[threadIdx.x] = s;
    __syncthreads();
    for (int off = 1; off < 256; off <<= 1) {
        int t = threadIdx.x >= off ? ls[threadIdx.x - off] : 0;
        __syncthreads();
        ls[threadIdx.x] += t;
        __syncthreads();
    }
    int run = ls[threadIdx.x] - s;
    if (threadIdx.x == 255) bsums[blockIdx.x] = ls[255];
#pragma unroll
    for (int k = 0; k < 16; k++) {
        int idx = tbase + k;
        if (idx < n) starts[idx] = run;
        run += v[k];
    }
}

__global__ void scan2(int* __restrict__ bsums, int nb, int* __restrict__ starts,
                      int n, int ne) {
    if (threadIdx.x == 0) {
        int run = 0;
        for (int b = 0; b < nb; b++) { int t = bsums[b]; bsums[b] = run; run += t; }
        starts[n] = ne;
    }
}

__global__ __launch_bounds__(256) void scan3(int* __restrict__ starts,
                                             const int* __restrict__ bsums, int n) {
    int i = blockIdx.x * 256 + threadIdx.x;
    if (i < n) starts[i] += bsums[i >> 12];
}

// --------------------- scatter src indices into CSR (rank-based) ---------
__global__ __launch_bounds__(256) void scatter4_kernel(const int* __restrict__ src,
                                                       const int* __restrict__ dst,
                                                       const int* __restrict__ starts,
                                                       const int* __restrict__ rank,
                                                       int* __restrict__ csr_src, int ne) {
    int i = blockIdx.x * 256 + threadIdx.x;
    int base = i * 4;
    if (base + 3 < ne) {
        int4 s = *(const int4*)(src + base);
        int4 d = *(const int4*)(dst + base);
        int4 r = *(const int4*)(rank + base);
        csr_src[starts[d.x] + r.x] = s.x;
        csr_src[starts[d.y] + r.y] = s.y;
        csr_src[starts[d.z] + r.z] = s.z;
        csr_src[starts[d.w] + r.w] = s.w;
    } else {
        for (int r = base; r < ne; r++)
            csr_src[starts[dst[r]] + rank[r]] = src[r];
    }
}

// ------------- fused: dot + online softmax + aggregation + elu -----------
// One wave per node. lane = (g,q): g = edge slot (0..3), q = channel quad.
// exp2-domain online softmax with wave-uniform fast path (no max growth ->
// no rescale). One dwordx4 gather per lane fetches 4 edge rows per iter.
__global__ __launch_bounds__(256) void fused_node(const float4* __restrict__ z4,
                                                  const int* __restrict__ starts,
                                                  const int* __restrict__ csr_src,
                                                  float4* __restrict__ out4, int n) {
    int node = blockIdx.x * 4 + (threadIdx.x >> 6);
    if (node >= n) return;
    int lane = threadIdx.x & 63;
    int g = lane >> 4;
    int q = lane & 15;
    int rs = starts[node], re = starts[node + 1];
    float4 zd = z4[(size_t)node * 16 + q];

    float m2 = -1e30f, denom = 0.f;
    float4 acc = make_float4(0.f, 0.f, 0.f, 0.f);

    for (int c = rs; c < re; c += 64) {
        int j = c + lane;
        int sv = j < re ? csr_src[j] : 0;
        int cn = min(64, re - c);
        int idx = g;
        bool val = idx < cn;
        int s = __shfl(sv, val ? idx : 0);
        float4 v = z4[(size_t)s * 16 + q];
        for (int k = 0; k < cn; k += 4) {
            int idx_n = k + 4 + g;
            bool val_n = idx_n < cn;
            int s_n = __shfl(sv, val_n ? idx_n : 0);
            float4 vn = z4[(size_t)s_n * 16 + q];
            float p = v.x * zd.x + v.y * zd.y + v.z * zd.z + v.w * zd.w;
#pragma unroll
            for (int msk = 1; msk < 16; msk <<= 1) p += __shfl_xor(p, msk);
            float e = p > 0.f ? p : SLOPE * p;
            float e2 = e * LOG2E;
            e2 = val ? e2 : -2e30f;
            if (__any(e2 > m2)) {                 // max grew somewhere: rescale
                float mnew = fmaxf(m2, e2);
                float sc = exp2f(m2 - mnew);      // ==0 on first edge
                float ex = exp2f(e2 - mnew);      // ==0 for invalid slots
                denom = fmaf(denom, sc, ex);
                acc.x = fmaf(acc.x, sc, ex * v.x);
                acc.y = fmaf(acc.y, sc, ex * v.y);
                acc.z = fmaf(acc.z, sc, ex * v.z);
                acc.w = fmaf(acc.w, sc, ex * v.w);
                m2 = mnew;
            } else {                              // fast path: no rescale
                float ex = exp2f(e2 - m2);
                denom += ex;
                acc.x = fmaf(ex, v.x, acc.x);
                acc.y = fmaf(ex, v.y, acc.y);
                acc.z = fmaf(ex, v.z, acc.z);
                acc.w = fmaf(ex, v.w, acc.w);
            }
            v = vn; val = val_n;
        }
    }
    // merge the 4 group states (same q across groups)
#pragma unroll
    for (int msk = 16; msk < 64; msk <<= 1) {
        float mo  = __shfl_xor(m2, msk);
        float dno = __shfl_xor(denom, msk);
        float ax = __shfl_xor(acc.x, msk);
        float ay = __shfl_xor(acc.y, msk);
        float az = __shfl_xor(acc.z, msk);
        float aw = __shfl_xor(acc.w, msk);
        float mnew = fmaxf(m2, mo);
        float ss = exp2f(m2 - mnew), so = exp2f(mo - mnew);
        denom = fmaf(denom, ss, dno * so);
        acc.x = fmaf(acc.x, ss, ax * so);
        acc.y = fmaf(acc.y, ss, ay * so);
        acc.z = fmaf(acc.z, ss, az * so);
        acc.w = fmaf(acc.w, ss, aw * so);
        m2 = mnew;
    }
    if (lane < 16) {
        float inv = denom > 0.f ? 1.f / denom : 0.f;
        float4 r; float x;
        x = acc.x * inv; r.x = x > 0.f ? x : __expf(x) - 1.f;
        x = acc.y * inv; r.y = x > 0.f ? x : __expf(x) - 1.f;
        x = acc.z * inv; r.z = x > 0.f ? x : __expf(x) - 1.f;
        x = acc.w * inv; r.w = x > 0.f ? x : __expf(x) - 1.f;
        out4[(size_t)node * 16 + q] = r;
    }
}

// -------------------------------------------------------------- launch ----
extern "C" void kernel_launch(void* const* d_in, const int* in_sizes, int n_in,
                              void* d_out, int out_size, void* d_ws, size_t ws_size,
                              hipStream_t stream) {
    const float* h   = (const float*)d_in[0];
    const float* W   = (const float*)d_in[1];
    const int*   src = (const int*)d_in[2];
    const int*   dst = (const int*)d_in[3];
    int n  = in_sizes[0] / 128;   // 100000
    int ne = in_sizes[2];         // 1600000

    float* z       = (float*)d_ws;                    // n*64 floats
    int*   starts  = (int*)(z + (size_t)n * 64);      // n+1 ints
    int*   cnt     = starts + (n + 1);                // n ints
    int*   rank    = cnt + n;                         // ne ints
    int*   csr_src = rank + ne;                       // ne ints
    int*   bsums   = csr_src + ne;                    // 32 ints

    int nb_gemm = ((n + 63) / 64) * 2;                // 3126 (covers ne/512 too)
    int nt4 = (ne + 3) / 4;
    int nb_scan = (n + 4095) / 4096;                  // 25

    hipMemsetAsync(cnt, 0, (size_t)n * sizeof(int), stream);
    gemm_hist_kernel<<<nb_gemm, 256, 0, stream>>>(h, W, z, dst, cnt, rank, n, ne);
    scan1<<<nb_scan, 256, 0, stream>>>(cnt, starts, bsums, n);
    scan2<<<1, 64, 0, stream>>>(bsums, nb_scan, starts, n, ne);
    scan3<<<(n + 255) / 256, 256, 0, stream>>>(starts, bsums, n);
    scatter4_kernel<<<(nt4 + 255) / 256, 256, 0, stream>>>(src, dst, starts, rank,
                                                           csr_src, ne);
    fused_node<<<(n + 3) / 4, 256, 0, stream>>>((const float4*)z, starts, csr_src,
                                                (float4*)d_out, n);
}